// Round 13
// baseline (201.225 us; speedup 1.0000x reference)
//
#include <hip/hip_runtime.h>
#include <stdint.h>

#define NSEQ 256
#define NRES 256
#define CM   256
#define CZ   128
#define CH   32
#define NHEAD 8
#define EPSF 1e-5f

typedef __bf16 bf16x8 __attribute__((ext_vector_type(8)));
typedef float  f32x4  __attribute__((ext_vector_type(4)));
typedef float  f32x16 __attribute__((ext_vector_type(16)));

__device__ __forceinline__ ushort f2bf(float f) {
    union { float f; uint32_t u; } v; v.f = f;
    uint32_t r = (v.u + 0x7FFFu + ((v.u >> 16) & 1u)) >> 16;
    return (ushort)r;
}
__device__ __forceinline__ float bf2f(ushort h) {
    union { uint32_t u; float f; } v; v.u = ((uint32_t)h) << 16;
    return v.f;
}
__device__ __forceinline__ float bfl(uint32_t u) {
    union { uint32_t x; float f; } v; v.x = u << 16; return v.f;
}
__device__ __forceinline__ float bfh(uint32_t u) {
    union { uint32_t x; float f; } v; v.x = u & 0xffff0000u; return v.f;
}
__device__ __forceinline__ unsigned int cvt_pk_bf16(float lo, float hi_) {
    unsigned int r;
    asm("v_cvt_pk_bf16_f32 %0, %1, %2" : "=v"(r) : "v"(lo), "v"(hi_));
    return r;
}

__device__ __forceinline__ void gload16(const void* g, void* l) {
    __builtin_amdgcn_global_load_lds(
        (const __attribute__((address_space(1))) void*)g,
        (__attribute__((address_space(3))) void*)l,
        16, 0, 0);
}

// -------------------------------------------------- fused pre-processing
// blocks [0,16384): LayerNorm(m) -> mn bf16
// blocks [16384,18432): LayerNorm(z)@Wz -> biasb bf16 (k-permuted)
// blocks [18432,19712): weight transpose/cast
__global__ __launch_bounds__(256) void pre_kernel(const float* __restrict__ m,
                                                  const float* __restrict__ ln_m_w,
                                                  const float* __restrict__ ln_m_b,
                                                  const float* __restrict__ z,
                                                  const float* __restrict__ ln_z_w,
                                                  const float* __restrict__ ln_z_b,
                                                  const float* __restrict__ Wz,
                                                  const float* __restrict__ Wq,
                                                  const float* __restrict__ Wk,
                                                  const float* __restrict__ Wv,
                                                  const float* __restrict__ Wg,
                                                  const float* __restrict__ Wo,
                                                  ushort* __restrict__ mn,
                                                  ushort* __restrict__ biasb,
                                                  ushort* __restrict__ Wt,
                                                  ushort* __restrict__ WoT) {
    int b = blockIdx.x;
    int t = threadIdx.x;
    int lane = t & 63;

    if (b < 16384) {
        // ---------------- LayerNorm(m)
        int gw = (b * 256 + t) >> 6;
        const float* row = m + (size_t)gw * 256;
        float4 x = *(const float4*)(row + lane * 4);
        float s  = x.x + x.y + x.z + x.w;
        float sq = x.x * x.x + x.y * x.y + x.z * x.z + x.w * x.w;
#pragma unroll
        for (int off = 32; off; off >>= 1) {
            s  += __shfl_xor(s, off, 64);
            sq += __shfl_xor(sq, off, 64);
        }
        float mu  = s * (1.0f / 256.0f);
        float var = sq * (1.0f / 256.0f) - mu * mu;
        float rs  = rsqrtf(var + EPSF);
        float4 wv = *(const float4*)(ln_m_w + lane * 4);
        float4 bv = *(const float4*)(ln_m_b + lane * 4);
        ushort4 o;
        o.x = f2bf((x.x - mu) * rs * wv.x + bv.x);
        o.y = f2bf((x.y - mu) * rs * wv.y + bv.y);
        o.z = f2bf((x.z - mu) * rs * wv.z + bv.z);
        o.w = f2bf((x.w - mu) * rs * wv.w + bv.w);
        *(ushort4*)(mn + (size_t)gw * 256 + lane * 4) = o;
    } else if (b < 18432) {
        // ---------------- LayerNorm(z) @ Wz -> bf16 bias, k-permuted
        int gw = ((b - 16384) * 256 + t) >> 6;
        float wz0[8], wz1[8];
#pragma unroll
        for (int h = 0; h < 8; ++h) {
            wz0[h] = Wz[(2 * lane) * 8 + h];
            wz1[h] = Wz[(2 * lane + 1) * 8 + h];
        }
        float w0 = ln_z_w[2 * lane], w1 = ln_z_w[2 * lane + 1];
        float b0 = ln_z_b[2 * lane], b1 = ln_z_b[2 * lane + 1];
        for (int row = gw; row < 65536; row += 8192) {
            float2 x = *(const float2*)(z + (size_t)row * 128 + 2 * lane);
            float s = x.x + x.y, sq = x.x * x.x + x.y * x.y;
#pragma unroll
            for (int off = 32; off; off >>= 1) {
                s  += __shfl_xor(s, off, 64);
                sq += __shfl_xor(sq, off, 64);
            }
            float mu = s * (1.0f / 128.0f);
            float rs = rsqrtf(sq * (1.0f / 128.0f) - mu * mu + EPSF);
            float z0 = (x.x - mu) * rs * w0 + b0;
            float z1 = (x.y - mu) * rs * w1 + b1;
            float acc[8];
#pragma unroll
            for (int h = 0; h < 8; ++h) acc[h] = z0 * wz0[h] + z1 * wz1[h];
            // packed butterfly: 8 heads x 64 lanes -> each lane one head sum
            float u[4];
#pragma unroll
            for (int i = 0; i < 4; ++i) {
                float send = (lane & 1) ? acc[i] : acc[i + 4];
                float rec  = __shfl_xor(send, 1, 64);
                u[i] = ((lane & 1) ? acc[i + 4] : acc[i]) + rec;
            }
            float v2[2];
#pragma unroll
            for (int i = 0; i < 2; ++i) {
                float send = (lane & 2) ? u[i] : u[i + 2];
                float rec  = __shfl_xor(send, 2, 64);
                v2[i] = ((lane & 2) ? u[i + 2] : u[i]) + rec;
            }
            float send = (lane & 4) ? v2[0] : v2[1];
            float rec  = __shfl_xor(send, 4, 64);
            float vv = ((lane & 4) ? v2[1] : v2[0]) + rec;
            vv += __shfl_xor(vv, 8, 64);
            vv += __shfl_xor(vv, 16, 64);
            vv += __shfl_xor(vv, 32, 64);
            if (lane < 8) {
                int hh = ((lane & 1) << 2) | (lane & 2) | ((lane >> 2) & 1);
                int jc = row & 31;
                int posv = ((jc & 4) << 2) | ((jc & 24) >> 1) | (jc & 3);
                biasb[hh * 65536 + (row & ~31) + posv] = f2bf(vv);
            }
        }
    } else {
        // ---------------- weight transpose/cast
        int n = b - 18432;
        int k = t;
        if (n < 1024) {
            int nn = n & 255;
            const float* src;
            float scale = 1.0f;
            if      (n < 256) { src = Wq; scale = 0.17677669529663687f; }
            else if (n < 512) { src = Wk; }
            else if (n < 768) { src = Wv; }
            else              { src = Wg; }
            Wt[n * 256 + k] = f2bf(src[k * 256 + nn] * scale);
        } else {
            int nn = n - 1024;
            WoT[nn * 256 + k] = f2bf(Wo[k * 256 + nn]);
        }
    }
}

// ------------------------------------------------------------ projection GEMM
// mn (65536x256) @ Wt^T -> Q,K (S,H,R,C); Vt (S,H,C,R); G2 [h][s][q][32] sigmoid
// BK=32 double-buffered (32 KB LDS -> up to 5 blocks/CU); 8 K-steps.
// Swizzle mask (row>>1)&3: in-order 8-lane batches cover all 8 16B slots of the
// 128B bank span (pos x parity) -> conflict-free ds_read_b128 (was 4-way).
// LDS-bounce epilogue -> 16B coalesced global stores (Q/K/G).
__global__ __launch_bounds__(256, 5) void proj_gemm_kernel(const ushort* __restrict__ mn,
                                                           const ushort* __restrict__ Wt,
                                                           const float* __restrict__ bg,
                                                           ushort* __restrict__ Q,
                                                           ushort* __restrict__ K,
                                                           ushort* __restrict__ Vt,
                                                           ushort* __restrict__ G) {
    __shared__ ushort SH[16384];          // 2 bufs x (A 4096 + B 4096) ushorts
    int bid = blockIdx.x;
    int wid = ((bid & 7) << 9) | (bid >> 3);
    int by = wid >> 3, bx = wid & 7;
    int m0 = by << 7, n0 = bx << 7;
    int t = threadIdx.x, lane = t & 63, w = t >> 6;
    int l15 = lane & 15, l4 = lane >> 4;
    int wr = w >> 1, wc = w & 1;

    int srow  = t >> 2;                                   // 0..63
    int sgran = t & 3;
    int scol  = (sgran ^ ((srow >> 1) & 3)) << 3;         // pre-swizzled source col
    const ushort* Ag = mn + (size_t)(m0 + srow) * 256 + scol;
    const ushort* Bg = Wt + (size_t)(n0 + srow) * 256 + scol;

    auto stage = [&](int kt) {
        int k0 = kt << 5;
        int bufo = (kt & 1) << 13;        // 8192 ushorts per buffer
        gload16(Ag + k0,             &SH[bufo + t * 8]);
        gload16(Ag + 64 * 256 + k0,  &SH[bufo + 2048 + t * 8]);
        gload16(Bg + k0,             &SH[bufo + 4096 + t * 8]);
        gload16(Bg + 64 * 256 + k0,  &SH[bufo + 4096 + 2048 + t * 8]);
    };

    f32x4 acc[4][4] = {};
    stage(0);

    int rg = (l4 ^ ((l15 >> 1) & 3)) << 3;   // read granule offset, const/lane

    for (int kt = 0; kt < 8; ++kt) {
        __syncthreads();                  // stage(kt) landed; prior buffer reads done
        if (kt < 7) stage(kt + 1);        // prefetch overlaps compute
        int bufo = (kt & 1) << 13;
        bf16x8 af[4], bfr[4];
#pragma unroll
        for (int mi = 0; mi < 4; ++mi) {
            int row = wr * 64 + mi * 16 + l15;
            af[mi] = *(const bf16x8*)&SH[bufo + row * 32 + rg];
        }
#pragma unroll
        for (int ni = 0; ni < 4; ++ni) {
            int row = wc * 64 + ni * 16 + l15;
            bfr[ni] = *(const bf16x8*)&SH[bufo + 4096 + row * 32 + rg];
        }
#pragma unroll
        for (int mi = 0; mi < 4; ++mi)
#pragma unroll
            for (int ni = 0; ni < 4; ++ni)
                acc[mi][ni] = __builtin_amdgcn_mfma_f32_16x16x32_bf16(af[mi], bfr[ni], acc[mi][ni], 0, 0, 0);
    }

    __syncthreads();                       // all LDS reads done; reuse SH

    int region = bx >> 1;
    int ss = m0 >> 8;

    if (region == 2) {
        int rbase = (m0 & 255) + wr * 64 + l4 * 4;
#pragma unroll
        for (int ni = 0; ni < 4; ++ni) {
            int nn = (n0 & 255) + wc * 64 + ni * 16 + l15;
            int h = nn >> 5, c = nn & 31;
#pragma unroll
            for (int mi = 0; mi < 4; ++mi) {
                int rr = rbase + mi * 16;
                ushort4 pv;
                pv.x = f2bf(acc[mi][ni][0]); pv.y = f2bf(acc[mi][ni][1]);
                pv.z = f2bf(acc[mi][ni][2]); pv.w = f2bf(acc[mi][ni][3]);
                *(ushort4*)&Vt[((size_t)(ss * 8 + h) * 32 + c) * 256 + rr] = pv;
            }
        }
    } else {
        // LDS bounce: wave-private 16x64 bf16 tile (stride 72), per mi-pass
        ushort* E = SH + w * 1152;
        int base_nn = (bx & 1) * 128 + wc * 64;
        int rloc = lane >> 2, seg = lane & 3;
#pragma unroll
        for (int mi = 0; mi < 4; ++mi) {
            if (region == 3) {
#pragma unroll
                for (int ni = 0; ni < 4; ++ni) {
                    float bgv = bg[base_nn + ni * 16 + l15];
#pragma unroll
                    for (int r = 0; r < 4; ++r) {
                        float x = acc[mi][ni][r] + bgv;
                        E[(l4 * 4 + r) * 72 + ni * 16 + l15] =
                            f2bf(1.0f / (1.0f + __expf(-x)));
                    }
                }
            } else {
#pragma unroll
                for (int ni = 0; ni < 4; ++ni)
#pragma unroll
                    for (int r = 0; r < 4; ++r)
                        E[(l4 * 4 + r) * 72 + ni * 16 + l15] = f2bf(acc[mi][ni][r]);
            }
            uint4 v0 = *(const uint4*)&E[rloc * 72 + seg * 16];
            uint4 v1 = *(const uint4*)&E[rloc * 72 + seg * 16 + 8];
            int rr  = (m0 & 255) + wr * 64 + mi * 16 + rloc;
            int nn0 = base_nn + seg * 16;
            int h0 = nn0 >> 5, c0 = nn0 & 31;
            int nn1 = nn0 + 8;
            int h1 = nn1 >> 5, c1 = nn1 & 31;
            if (region <= 1) {
                ushort* dst = (region == 0) ? Q : K;
                *(uint4*)&dst[(size_t)(ss * 8 + h0) * 8192 + rr * 32 + c0] = v0;
                *(uint4*)&dst[(size_t)(ss * 8 + h1) * 8192 + rr * 32 + c1] = v1;
            } else {
                *(uint4*)&G[((size_t)h0 << 21) + (ss << 13) + (rr << 5) + c0] = v0;
                *(uint4*)&G[((size_t)h1 << 21) + (ss << 13) + (rr << 5) + c1] = v1;
            }
        }
    }
}

// ----------------------------------------------------------------- attention
// 512 blocks, 8 waves x 32 q-rows, 4 (s,h) iterations, 8 k-chunks of 32.
// No-max softmax; bf16 bias (lane-permuted, 2x16B loads/chunk); unroll-2 kt
// loop for cross-chunk ILP; permlane32_swap P-fragments; dbuf K/V LDS.
__global__ __launch_bounds__(512, 4) void attn_kernel(const ushort* __restrict__ Q,
                                                      const ushort* __restrict__ K,
                                                      const ushort* __restrict__ Vt,
                                                      const ushort* __restrict__ G,
                                                      const ushort* __restrict__ biasb,
                                                      ushort* __restrict__ GO) {
    __shared__ ushort smem[32768];   // 2 x (K 16KB + V 16KB)
    const int t = threadIdx.x;
    const int lane = t & 63, w = t >> 6;
    const int l31 = lane & 31, hi = lane >> 5;
    const int h = blockIdx.x & 7, s0 = blockIdx.x >> 3;   // s0 in [0,64)
    const int q0 = w * 32;

    auto stage = [&](int i) {
        size_t shb = (size_t)((i * 64 + s0) * 8 + h) * 8192;
        const ushort* Kg = K + shb;
        const ushort* Vg = Vt + shb;
        int bufo = (i & 1) * 16384;
#pragma unroll
        for (int rd = 0; rd < 2; ++rd) {
            int g1 = rd * 512 + t;
            int kk = g1 >> 2;
            int lgk = (g1 & 3) ^ ((kk >> 1) & 3);          // K XOR-swizzle (pre-swizzled source)
            gload16(Kg + kk * 32 + lgk * 8, &smem[bufo + g1 * 8]);
            int cc = g1 >> 5;
            int lgv = (g1 & 31) ^ (cc & 7);                // V XOR-swizzle
            gload16(Vg + cc * 256 + lgv * 8, &smem[bufo + 8192 + g1 * 8]);
        }
    };

    stage(0);

    for (int i = 0; i < 4; ++i) {
        __syncthreads();                 // drains vmcnt(0)+lgkmcnt(0), full fence
        if (i < 3) stage(i + 1);         // async prefetch into other buffer

        const int s = i * 64 + s0;
        const size_t shb = (size_t)(s * 8 + h) * 8192;
        const int bufo = (i & 1) * 16384;

        // Q fragments (B-operand): col=q=l31, c = chalf*16 + hi*8 + j
        bf16x8 qf0 = *(const bf16x8*)&Q[shb + (size_t)(q0 + l31) * 32 + hi * 8];
        bf16x8 qf1 = *(const bf16x8*)&Q[shb + (size_t)(q0 + l31) * 32 + 16 + hi * 8];

        // bf16 bias, permuted layout: lane's 16 values contiguous at hi*16
        const ushort* bp = biasb + (size_t)h * 65536 + (size_t)(q0 + l31) * 256 + hi * 16;
        const int vbase = bufo + 8192 + l31 * 256;
        const int vswz = l31 & 7;

        float l_run = 0.f;               // per-lane partial over its 128 keys
        f32x16 oa = {}, ob = {};

#pragma unroll 2
        for (int kt = 0; kt < 8; ++kt) {
            // bias as MFMA C-in for this 32-key chunk (bf16 -> fp32 unpack)
            uint4 b0 = *(const uint4*)&bp[kt * 32];
            uint4 b1 = *(const uint4*)&bp[kt * 32 + 8];
            f32x16 sa;
            sa[0]  = bfl(b0.x); sa[1]  = bfh(b0.x);
            sa[2]  = bfl(b0.y); sa[3]  = bfh(b0.y);
            sa[4]  = bfl(b0.z); sa[5]  = bfh(b0.z);
            sa[6]  = bfl(b0.w); sa[7]  = bfh(b0.w);
            sa[8]  = bfl(b1.x); sa[9]  = bfh(b1.x);
            sa[10] = bfl(b1.y); sa[11] = bfh(b1.y);
            sa[12] = bfl(b1.z); sa[13] = bfh(b1.z);
            sa[14] = bfl(b1.w); sa[15] = bfh(b1.w);

            // QK^T swapped: S^T chunk = K_chunk · Q^T (+bias)
            int krow = kt * 32 + l31;
            int swz = (krow >> 1) & 3;
            int rb = bufo + krow * 32;
            bf16x8 kf0 = *(const bf16x8*)&smem[rb + ((hi ^ swz) << 3)];
            bf16x8 kf1 = *(const bf16x8*)&smem[rb + (((2 + hi) ^ swz) << 3)];
            sa = __builtin_amdgcn_mfma_f32_32x32x16_bf16(kf0, qf0, sa, 0, 0, 0);
            sa = __builtin_amdgcn_mfma_f32_32x32x16_bf16(kf1, qf1, sa, 0, 0, 0);

            // exp (no max subtraction), per-lane sum accumulation
            float ls0 = 0.f, ls1 = 0.f;
#pragma unroll
            for (int r = 0; r < 16; r += 2) {
                float p0 = __expf(sa[r]);
                float p1 = __expf(sa[r + 1]);
                sa[r] = p0; sa[r + 1] = p1;
                ls0 += p0; ls1 += p1;
            }
            l_run += ls0 + ls1;

            // P -> bf16 packed words; permlane32_swap builds both fragment words
            unsigned int w0[4], w1[4];
#pragma unroll
            for (int mm = 0; mm < 4; ++mm) {
                w0[mm] = cvt_pk_bf16(sa[4 * mm + 0], sa[4 * mm + 1]);
                w1[mm] = cvt_pk_bf16(sa[4 * mm + 2], sa[4 * mm + 3]);
            }
#pragma unroll
            for (int hh = 0; hh < 2; ++hh) {
                unsigned int F0 = w0[2 * hh], H0 = w0[2 * hh + 1];
                unsigned int F1 = w1[2 * hh], H1 = w1[2 * hh + 1];
                asm("v_permlane32_swap_b32 %0, %1" : "+v"(F0), "+v"(H0));
                asm("v_permlane32_swap_b32 %0, %1" : "+v"(F1), "+v"(H1));
                uint4 fw = make_uint4(F0, F1, H0, H1);
                bf16x8 pf = *(bf16x8*)&fw;
                int g = kt * 4 + hh * 2 + hi;
                bf16x8 vf = *(const bf16x8*)&smem[vbase + ((g ^ vswz) << 3)];
                if (hh) ob = __builtin_amdgcn_mfma_f32_32x32x16_bf16(vf, pf, ob, 0, 0, 0);
                else    oa = __builtin_amdgcn_mfma_f32_32x32x16_bf16(vf, pf, oa, 0, 0, 0);
            }
        }

        l_run += __shfl_xor(l_run, 32, 64);
        float rinv = 1.0f / l_run;

        // epilogue: G2/GO2 [h][s][q][32]; o[r] -> c = 4*hi + (r&3) + 8*(r>>2)
        const size_t grow = ((size_t)h << 21) + ((size_t)s << 13) + ((q0 + l31) << 5) + hi * 4;
#pragma unroll
        for (int g = 0; g < 4; ++g) {
            ushort4 gv = *(const ushort4*)&G[grow + g * 8];
            float o0 = (oa[4 * g + 0] + ob[4 * g + 0]) * rinv * bf2f(gv.x);
            float o1 = (oa[4 * g + 1] + ob[4 * g + 1]) * rinv * bf2f(gv.y);
            float o2 = (oa[4 * g + 2] + ob[4 * g + 2]) * rinv * bf2f(gv.z);
            float o3 = (oa[4 * g + 3] + ob[4 * g + 3]) * rinv * bf2f(gv.w);
            ushort4 ov;
            ov.x = f2bf(o0); ov.y = f2bf(o1); ov.z = f2bf(o2); ov.w = f2bf(o3);
            *(ushort4*)&GO[grow + g * 8] = ov;
        }
    }
}

// -------------------------------------------------------------- output GEMM
// GO2 [h][m][32] (m = s*256+q) @ WoT^T + bo -> out fp32; 128x128 tile,
// double-buffered LDS staging (BK=64).
__global__ __launch_bounds__(256) void out_gemm_kernel(const ushort* __restrict__ GO,
                                                       const ushort* __restrict__ WoT,
                                                       const float* __restrict__ bo,
                                                       float* __restrict__ out) {
    __shared__ ushort SH[32768];
    int bid = blockIdx.x;
    int wid = ((bid & 7) << 7) | (bid >> 3);
    int by = wid >> 1, bx = wid & 1;
    int m0 = by << 7, n0 = bx << 7;
    int t = threadIdx.x, lane = t & 63, w = t >> 6;
    int l15 = lane & 15, l4 = lane >> 4;
    int wr = w >> 1, wc = w & 1;

    int srow  = t >> 3;
    int scolh = (((lane & 7) ^ ((lane >> 3) & 7)) << 3);
    // A element (m, k): addr = (k>>5)<<21 | m<<5 | (k&31); k = kt*64 + scolh
    const ushort* Ag = GO + ((size_t)(scolh >> 5) << 21) + ((size_t)(m0 + srow) << 5) + (scolh & 31);
    const ushort* Bg = WoT + (size_t)(n0 + srow) * 256 + scolh;

    auto stage = [&](int kt) {
        int k0 = kt << 6;
        int bufo = (kt & 1) << 14;
#pragma unroll
        for (int i = 0; i < 4; ++i) {
            gload16(Ag + ((size_t)kt << 22) + (i << 10), &SH[bufo + t * 8 + i * 2048]);
            gload16(Bg + (size_t)(i * 32) * 256 + k0, &SH[bufo + 8192 + t * 8 + i * 2048]);
        }
    };

    f32x4 acc[4][4] = {};
    stage(0);

    for (int kt = 0; kt < 4; ++kt) {
        __syncthreads();
        if (kt < 3) stage(kt + 1);
        int bufo = (kt & 1) << 14;
#pragma unroll
        for (int ks = 0; ks < 2; ++ks) {
            int xr = ks * 4 + l4;
            bf16x8 af[4], bfr[4];
#pragma unroll
            for (int mi = 0; mi < 4; ++mi) {
                int row = wr * 64 + mi * 16 + l15;
                af[mi] = *(const bf16x8*)&SH[bufo + row * 64 + ((xr ^ (l15 & 7)) << 3)];
            }
#pragma unroll
            for (int ni = 0; ni < 4; ++ni) {
                int row = wc * 64 + ni * 16 + l15;
                bfr[ni] = *(const bf16x8*)&SH[bufo + 8192 + row * 64 + ((xr ^ (l15 & 7)) << 3)];
            }
#pragma unroll
            for (int mi = 0; mi < 4; ++mi)
#pragma unroll
                for (int ni = 0; ni < 4; ++ni)
                    acc[mi][ni] = __builtin_amdgcn_mfma_f32_16x16x32_bf16(af[mi], bfr[ni], acc[mi][ni], 0, 0, 0);
        }
    }

    int crow0 = m0 + wr * 64 + l4 * 4;
#pragma unroll
    for (int ni = 0; ni < 4; ++ni) {
        int col = n0 + wc * 64 + ni * 16 + l15;
        float bov = bo[col];
#pragma unroll
        for (int mi = 0; mi < 4; ++mi)
#pragma unroll
            for (int r = 0; r < 4; ++r)
                out[(size_t)(crow0 + mi * 16 + r) * 256 + col] = acc[mi][ni][r] + bov;
    }
}

// ------------------------------------------------------------------- launch
extern "C" void kernel_launch(void* const* d_in, const int* in_sizes, int n_in,
                              void* d_out, int out_size, void* d_ws, size_t ws_size,
                              hipStream_t stream) {
    const float* m      = (const float*)d_in[0];
    const float* z      = (const float*)d_in[1];
    const float* ln_m_w = (const float*)d_in[2];
    const float* ln_m_b = (const float*)d_in[3];
    const float* ln_z_w = (const float*)d_in[4];
    const float* ln_z_b = (const float*)d_in[5];
    const float* Wz     = (const float*)d_in[6];
    const float* Wq     = (const float*)d_in[7];
    const float* Wk     = (const float*)d_in[8];
    const float* Wv     = (const float*)d_in[9];
    const float* Wg     = (const float*)d_in[10];
    const float* bg     = (const float*)d_in[11];
    const float* Wo     = (const float*)d_in[12];
    const float* bo     = (const float*)d_in[13];
    float* out = (float*)d_out;

    char* ws = (char*)d_ws;
    ushort* Wt    = (ushort*)(ws + 0);            //  524288 B
    ushort* WoT   = (ushort*)(ws + 524288);       //  131072 B
    ushort* biasb = (ushort*)(ws + 655360);       // 1048576 B (bf16, region reserves 2MB)
    ushort* mn    = (ushort*)(ws + 2752512);      // 33554432 B (aliased with GO)
    ushort* GO    = mn;
    ushort* Q     = (ushort*)(ws + 36306944);     // 33554432 B
    ushort* K     = (ushort*)(ws + 69861376);     // 33554432 B
    ushort* Vt    = (ushort*)(ws + 103415808);    // 33554432 B
    ushort* G     = (ushort*)(ws + 136970240);    // 33554432 B

    pre_kernel<<<19712, 256, 0, stream>>>(m, ln_m_w, ln_m_b, z, ln_z_w, ln_z_b,
                                          Wz, Wq, Wk, Wv, Wg, Wo,
                                          mn, biasb, Wt, WoT);
    proj_gemm_kernel<<<4096, 256, 0, stream>>>(mn, Wt, bg, Q, K, Vt, G);
    attn_kernel<<<512, 512, 0, stream>>>(Q, K, Vt, G, biasb, GO);
    out_gemm_kernel<<<1024, 256, 0, stream>>>(GO, WoT, bo, out);
}

// Round 14
// 189.985 us; speedup vs baseline: 1.0592x; 1.0592x over previous
//
#include <hip/hip_runtime.h>
#include <stdint.h>

#define NSEQ 256
#define NRES 256
#define CM   256
#define CZ   128
#define CH   32
#define NHEAD 8
#define EPSF 1e-5f

typedef __bf16 bf16x8 __attribute__((ext_vector_type(8)));
typedef float  f32x4  __attribute__((ext_vector_type(4)));
typedef float  f32x16 __attribute__((ext_vector_type(16)));

__device__ __forceinline__ ushort f2bf(float f) {
    union { float f; uint32_t u; } v; v.f = f;
    uint32_t r = (v.u + 0x7FFFu + ((v.u >> 16) & 1u)) >> 16;
    return (ushort)r;
}
__device__ __forceinline__ float bf2f(ushort h) {
    union { uint32_t u; float f; } v; v.u = ((uint32_t)h) << 16;
    return v.f;
}
__device__ __forceinline__ float bfl(uint32_t u) {
    union { uint32_t x; float f; } v; v.x = u << 16; return v.f;
}
__device__ __forceinline__ float bfh(uint32_t u) {
    union { uint32_t x; float f; } v; v.x = u & 0xffff0000u; return v.f;
}
__device__ __forceinline__ unsigned int cvt_pk_bf16(float lo, float hi_) {
    unsigned int r;
    asm("v_cvt_pk_bf16_f32 %0, %1, %2" : "=v"(r) : "v"(lo), "v"(hi_));
    return r;
}

__device__ __forceinline__ void gload16(const void* g, void* l) {
    __builtin_amdgcn_global_load_lds(
        (const __attribute__((address_space(1))) void*)g,
        (__attribute__((address_space(3))) void*)l,
        16, 0, 0);
}

// -------------------------------------------------- fused pre-processing
// blocks [0,16384): LayerNorm(m) -> mn bf16
// blocks [16384,18432): LayerNorm(z)@Wz -> biasb bf16 (k-permuted)
// blocks [18432,19712): weight transpose/cast
__global__ __launch_bounds__(256) void pre_kernel(const float* __restrict__ m,
                                                  const float* __restrict__ ln_m_w,
                                                  const float* __restrict__ ln_m_b,
                                                  const float* __restrict__ z,
                                                  const float* __restrict__ ln_z_w,
                                                  const float* __restrict__ ln_z_b,
                                                  const float* __restrict__ Wz,
                                                  const float* __restrict__ Wq,
                                                  const float* __restrict__ Wk,
                                                  const float* __restrict__ Wv,
                                                  const float* __restrict__ Wg,
                                                  const float* __restrict__ Wo,
                                                  ushort* __restrict__ mn,
                                                  ushort* __restrict__ biasb,
                                                  ushort* __restrict__ Wt,
                                                  ushort* __restrict__ WoT) {
    int b = blockIdx.x;
    int t = threadIdx.x;
    int lane = t & 63;

    if (b < 16384) {
        // ---------------- LayerNorm(m)
        int gw = (b * 256 + t) >> 6;
        const float* row = m + (size_t)gw * 256;
        float4 x = *(const float4*)(row + lane * 4);
        float s  = x.x + x.y + x.z + x.w;
        float sq = x.x * x.x + x.y * x.y + x.z * x.z + x.w * x.w;
#pragma unroll
        for (int off = 32; off; off >>= 1) {
            s  += __shfl_xor(s, off, 64);
            sq += __shfl_xor(sq, off, 64);
        }
        float mu  = s * (1.0f / 256.0f);
        float var = sq * (1.0f / 256.0f) - mu * mu;
        float rs  = rsqrtf(var + EPSF);
        float4 wv = *(const float4*)(ln_m_w + lane * 4);
        float4 bv = *(const float4*)(ln_m_b + lane * 4);
        ushort4 o;
        o.x = f2bf((x.x - mu) * rs * wv.x + bv.x);
        o.y = f2bf((x.y - mu) * rs * wv.y + bv.y);
        o.z = f2bf((x.z - mu) * rs * wv.z + bv.z);
        o.w = f2bf((x.w - mu) * rs * wv.w + bv.w);
        *(ushort4*)(mn + (size_t)gw * 256 + lane * 4) = o;
    } else if (b < 18432) {
        // ---------------- LayerNorm(z) @ Wz -> bf16 bias, k-permuted
        int gw = ((b - 16384) * 256 + t) >> 6;
        float wz0[8], wz1[8];
#pragma unroll
        for (int h = 0; h < 8; ++h) {
            wz0[h] = Wz[(2 * lane) * 8 + h];
            wz1[h] = Wz[(2 * lane + 1) * 8 + h];
        }
        float w0 = ln_z_w[2 * lane], w1 = ln_z_w[2 * lane + 1];
        float b0 = ln_z_b[2 * lane], b1 = ln_z_b[2 * lane + 1];
        for (int row = gw; row < 65536; row += 8192) {
            float2 x = *(const float2*)(z + (size_t)row * 128 + 2 * lane);
            float s = x.x + x.y, sq = x.x * x.x + x.y * x.y;
#pragma unroll
            for (int off = 32; off; off >>= 1) {
                s  += __shfl_xor(s, off, 64);
                sq += __shfl_xor(sq, off, 64);
            }
            float mu = s * (1.0f / 128.0f);
            float rs = rsqrtf(sq * (1.0f / 128.0f) - mu * mu + EPSF);
            float z0 = (x.x - mu) * rs * w0 + b0;
            float z1 = (x.y - mu) * rs * w1 + b1;
            float acc[8];
#pragma unroll
            for (int h = 0; h < 8; ++h) acc[h] = z0 * wz0[h] + z1 * wz1[h];
            // packed butterfly: 8 heads x 64 lanes -> each lane one head sum
            float u[4];
#pragma unroll
            for (int i = 0; i < 4; ++i) {
                float send = (lane & 1) ? acc[i] : acc[i + 4];
                float rec  = __shfl_xor(send, 1, 64);
                u[i] = ((lane & 1) ? acc[i + 4] : acc[i]) + rec;
            }
            float v2[2];
#pragma unroll
            for (int i = 0; i < 2; ++i) {
                float send = (lane & 2) ? u[i] : u[i + 2];
                float rec  = __shfl_xor(send, 2, 64);
                v2[i] = ((lane & 2) ? u[i + 2] : u[i]) + rec;
            }
            float send = (lane & 4) ? v2[0] : v2[1];
            float rec  = __shfl_xor(send, 4, 64);
            float vv = ((lane & 4) ? v2[1] : v2[0]) + rec;
            vv += __shfl_xor(vv, 8, 64);
            vv += __shfl_xor(vv, 16, 64);
            vv += __shfl_xor(vv, 32, 64);
            if (lane < 8) {
                int hh = ((lane & 1) << 2) | (lane & 2) | ((lane >> 2) & 1);
                int jc = row & 31;
                int posv = ((jc & 4) << 2) | ((jc & 24) >> 1) | (jc & 3);
                biasb[hh * 65536 + (row & ~31) + posv] = f2bf(vv);
            }
        }
    } else {
        // ---------------- weight transpose/cast
        int n = b - 18432;
        int k = t;
        if (n < 1024) {
            int nn = n & 255;
            const float* src;
            float scale = 1.0f;
            if      (n < 256) { src = Wq; scale = 0.17677669529663687f; }
            else if (n < 512) { src = Wk; }
            else if (n < 768) { src = Wv; }
            else              { src = Wg; }
            Wt[n * 256 + k] = f2bf(src[k * 256 + nn] * scale);
        } else {
            int nn = n - 1024;
            WoT[nn * 256 + k] = f2bf(Wo[k * 256 + nn]);
        }
    }
}

// ------------------------------------------------------------ projection GEMM
// mn (65536x256) @ Wt^T -> Q,K (S,H,R,C); Vt (S,H,C,R); G2 [h][s][q][32] sigmoid
// BK=32 double-buffered (32 KB LDS, 4 blocks/CU); 8 K-steps.
// Swizzle mask (row>>1)&3: conflict-free ds_read_b128 (r13: conflicts 4.59M->0.39M).
// launch_bounds (256,4): r13's (256,5) forced VGPR 60->48 -> 49MB spill, slower.
// LDS-bounce epilogue -> 16B coalesced global stores (Q/K/G).
__global__ __launch_bounds__(256, 4) void proj_gemm_kernel(const ushort* __restrict__ mn,
                                                           const ushort* __restrict__ Wt,
                                                           const float* __restrict__ bg,
                                                           ushort* __restrict__ Q,
                                                           ushort* __restrict__ K,
                                                           ushort* __restrict__ Vt,
                                                           ushort* __restrict__ G) {
    __shared__ ushort SH[16384];          // 2 bufs x (A 4096 + B 4096) ushorts
    int bid = blockIdx.x;
    int wid = ((bid & 7) << 9) | (bid >> 3);
    int by = wid >> 3, bx = wid & 7;
    int m0 = by << 7, n0 = bx << 7;
    int t = threadIdx.x, lane = t & 63, w = t >> 6;
    int l15 = lane & 15, l4 = lane >> 4;
    int wr = w >> 1, wc = w & 1;

    int srow  = t >> 2;                                   // 0..63
    int sgran = t & 3;
    int scol  = (sgran ^ ((srow >> 1) & 3)) << 3;         // pre-swizzled source col
    const ushort* Ag = mn + (size_t)(m0 + srow) * 256 + scol;
    const ushort* Bg = Wt + (size_t)(n0 + srow) * 256 + scol;

    auto stage = [&](int kt) {
        int k0 = kt << 5;
        int bufo = (kt & 1) << 13;        // 8192 ushorts per buffer
        gload16(Ag + k0,             &SH[bufo + t * 8]);
        gload16(Ag + 64 * 256 + k0,  &SH[bufo + 2048 + t * 8]);
        gload16(Bg + k0,             &SH[bufo + 4096 + t * 8]);
        gload16(Bg + 64 * 256 + k0,  &SH[bufo + 4096 + 2048 + t * 8]);
    };

    f32x4 acc[4][4] = {};
    stage(0);

    int rg = (l4 ^ ((l15 >> 1) & 3)) << 3;   // read granule offset, const/lane

    for (int kt = 0; kt < 8; ++kt) {
        __syncthreads();                  // stage(kt) landed; prior buffer reads done
        if (kt < 7) stage(kt + 1);        // prefetch overlaps compute
        int bufo = (kt & 1) << 13;
        bf16x8 af[4], bfr[4];
#pragma unroll
        for (int mi = 0; mi < 4; ++mi) {
            int row = wr * 64 + mi * 16 + l15;
            af[mi] = *(const bf16x8*)&SH[bufo + row * 32 + rg];
        }
#pragma unroll
        for (int ni = 0; ni < 4; ++ni) {
            int row = wc * 64 + ni * 16 + l15;
            bfr[ni] = *(const bf16x8*)&SH[bufo + 4096 + row * 32 + rg];
        }
#pragma unroll
        for (int mi = 0; mi < 4; ++mi)
#pragma unroll
            for (int ni = 0; ni < 4; ++ni)
                acc[mi][ni] = __builtin_amdgcn_mfma_f32_16x16x32_bf16(af[mi], bfr[ni], acc[mi][ni], 0, 0, 0);
    }

    __syncthreads();                       // all LDS reads done; reuse SH

    int region = bx >> 1;
    int ss = m0 >> 8;

    if (region == 2) {
        int rbase = (m0 & 255) + wr * 64 + l4 * 4;
#pragma unroll
        for (int ni = 0; ni < 4; ++ni) {
            int nn = (n0 & 255) + wc * 64 + ni * 16 + l15;
            int h = nn >> 5, c = nn & 31;
#pragma unroll
            for (int mi = 0; mi < 4; ++mi) {
                int rr = rbase + mi * 16;
                ushort4 pv;
                pv.x = f2bf(acc[mi][ni][0]); pv.y = f2bf(acc[mi][ni][1]);
                pv.z = f2bf(acc[mi][ni][2]); pv.w = f2bf(acc[mi][ni][3]);
                *(ushort4*)&Vt[((size_t)(ss * 8 + h) * 32 + c) * 256 + rr] = pv;
            }
        }
    } else {
        // LDS bounce: wave-private 16x64 bf16 tile (stride 72), per mi-pass
        ushort* E = SH + w * 1152;
        int base_nn = (bx & 1) * 128 + wc * 64;
        int rloc = lane >> 2, seg = lane & 3;
#pragma unroll
        for (int mi = 0; mi < 4; ++mi) {
            if (region == 3) {
#pragma unroll
                for (int ni = 0; ni < 4; ++ni) {
                    float bgv = bg[base_nn + ni * 16 + l15];
#pragma unroll
                    for (int r = 0; r < 4; ++r) {
                        float x = acc[mi][ni][r] + bgv;
                        E[(l4 * 4 + r) * 72 + ni * 16 + l15] =
                            f2bf(1.0f / (1.0f + __expf(-x)));
                    }
                }
            } else {
#pragma unroll
                for (int ni = 0; ni < 4; ++ni)
#pragma unroll
                    for (int r = 0; r < 4; ++r)
                        E[(l4 * 4 + r) * 72 + ni * 16 + l15] = f2bf(acc[mi][ni][r]);
            }
            uint4 v0 = *(const uint4*)&E[rloc * 72 + seg * 16];
            uint4 v1 = *(const uint4*)&E[rloc * 72 + seg * 16 + 8];
            int rr  = (m0 & 255) + wr * 64 + mi * 16 + rloc;
            int nn0 = base_nn + seg * 16;
            int h0 = nn0 >> 5, c0 = nn0 & 31;
            int nn1 = nn0 + 8;
            int h1 = nn1 >> 5, c1 = nn1 & 31;
            if (region <= 1) {
                ushort* dst = (region == 0) ? Q : K;
                *(uint4*)&dst[(size_t)(ss * 8 + h0) * 8192 + rr * 32 + c0] = v0;
                *(uint4*)&dst[(size_t)(ss * 8 + h1) * 8192 + rr * 32 + c1] = v1;
            } else {
                *(uint4*)&G[((size_t)h0 << 21) + (ss << 13) + (rr << 5) + c0] = v0;
                *(uint4*)&G[((size_t)h1 << 21) + (ss << 13) + (rr << 5) + c1] = v1;
            }
        }
    }
}

// ----------------------------------------------------------------- attention
// 512 blocks, 8 waves x 32 q-rows, 4 (s,h) iterations, 8 k-chunks of 32.
// No-max softmax; bf16 bias (lane-permuted, 2x16B loads/chunk); unroll-2 kt
// loop for cross-chunk ILP; permlane32_swap P-fragments; dbuf K/V LDS.
__global__ __launch_bounds__(512, 4) void attn_kernel(const ushort* __restrict__ Q,
                                                      const ushort* __restrict__ K,
                                                      const ushort* __restrict__ Vt,
                                                      const ushort* __restrict__ G,
                                                      const ushort* __restrict__ biasb,
                                                      ushort* __restrict__ GO) {
    __shared__ ushort smem[32768];   // 2 x (K 16KB + V 16KB)
    const int t = threadIdx.x;
    const int lane = t & 63, w = t >> 6;
    const int l31 = lane & 31, hi = lane >> 5;
    const int h = blockIdx.x & 7, s0 = blockIdx.x >> 3;   // s0 in [0,64)
    const int q0 = w * 32;

    auto stage = [&](int i) {
        size_t shb = (size_t)((i * 64 + s0) * 8 + h) * 8192;
        const ushort* Kg = K + shb;
        const ushort* Vg = Vt + shb;
        int bufo = (i & 1) * 16384;
#pragma unroll
        for (int rd = 0; rd < 2; ++rd) {
            int g1 = rd * 512 + t;
            int kk = g1 >> 2;
            int lgk = (g1 & 3) ^ ((kk >> 1) & 3);          // K XOR-swizzle (pre-swizzled source)
            gload16(Kg + kk * 32 + lgk * 8, &smem[bufo + g1 * 8]);
            int cc = g1 >> 5;
            int lgv = (g1 & 31) ^ (cc & 7);                // V XOR-swizzle
            gload16(Vg + cc * 256 + lgv * 8, &smem[bufo + 8192 + g1 * 8]);
        }
    };

    stage(0);

    for (int i = 0; i < 4; ++i) {
        __syncthreads();                 // drains vmcnt(0)+lgkmcnt(0), full fence
        if (i < 3) stage(i + 1);         // async prefetch into other buffer

        const int s = i * 64 + s0;
        const size_t shb = (size_t)(s * 8 + h) * 8192;
        const int bufo = (i & 1) * 16384;

        // Q fragments (B-operand): col=q=l31, c = chalf*16 + hi*8 + j
        bf16x8 qf0 = *(const bf16x8*)&Q[shb + (size_t)(q0 + l31) * 32 + hi * 8];
        bf16x8 qf1 = *(const bf16x8*)&Q[shb + (size_t)(q0 + l31) * 32 + 16 + hi * 8];

        // bf16 bias, permuted layout: lane's 16 values contiguous at hi*16
        const ushort* bp = biasb + (size_t)h * 65536 + (size_t)(q0 + l31) * 256 + hi * 16;
        const int vbase = bufo + 8192 + l31 * 256;
        const int vswz = l31 & 7;

        float l_run = 0.f;               // per-lane partial over its 128 keys
        f32x16 oa = {}, ob = {};

#pragma unroll 2
        for (int kt = 0; kt < 8; ++kt) {
            // bias as MFMA C-in for this 32-key chunk (bf16 -> fp32 unpack)
            uint4 b0 = *(const uint4*)&bp[kt * 32];
            uint4 b1 = *(const uint4*)&bp[kt * 32 + 8];
            f32x16 sa;
            sa[0]  = bfl(b0.x); sa[1]  = bfh(b0.x);
            sa[2]  = bfl(b0.y); sa[3]  = bfh(b0.y);
            sa[4]  = bfl(b0.z); sa[5]  = bfh(b0.z);
            sa[6]  = bfl(b0.w); sa[7]  = bfh(b0.w);
            sa[8]  = bfl(b1.x); sa[9]  = bfh(b1.x);
            sa[10] = bfl(b1.y); sa[11] = bfh(b1.y);
            sa[12] = bfl(b1.z); sa[13] = bfh(b1.z);
            sa[14] = bfl(b1.w); sa[15] = bfh(b1.w);

            // QK^T swapped: S^T chunk = K_chunk · Q^T (+bias)
            int krow = kt * 32 + l31;
            int swz = (krow >> 1) & 3;
            int rb = bufo + krow * 32;
            bf16x8 kf0 = *(const bf16x8*)&smem[rb + ((hi ^ swz) << 3)];
            bf16x8 kf1 = *(const bf16x8*)&smem[rb + (((2 + hi) ^ swz) << 3)];
            sa = __builtin_amdgcn_mfma_f32_32x32x16_bf16(kf0, qf0, sa, 0, 0, 0);
            sa = __builtin_amdgcn_mfma_f32_32x32x16_bf16(kf1, qf1, sa, 0, 0, 0);

            // exp (no max subtraction), per-lane sum accumulation
            float ls0 = 0.f, ls1 = 0.f;
#pragma unroll
            for (int r = 0; r < 16; r += 2) {
                float p0 = __expf(sa[r]);
                float p1 = __expf(sa[r + 1]);
                sa[r] = p0; sa[r + 1] = p1;
                ls0 += p0; ls1 += p1;
            }
            l_run += ls0 + ls1;

            // P -> bf16 packed words; permlane32_swap builds both fragment words
            unsigned int w0[4], w1[4];
#pragma unroll
            for (int mm = 0; mm < 4; ++mm) {
                w0[mm] = cvt_pk_bf16(sa[4 * mm + 0], sa[4 * mm + 1]);
                w1[mm] = cvt_pk_bf16(sa[4 * mm + 2], sa[4 * mm + 3]);
            }
#pragma unroll
            for (int hh = 0; hh < 2; ++hh) {
                unsigned int F0 = w0[2 * hh], H0 = w0[2 * hh + 1];
                unsigned int F1 = w1[2 * hh], H1 = w1[2 * hh + 1];
                asm("v_permlane32_swap_b32 %0, %1" : "+v"(F0), "+v"(H0));
                asm("v_permlane32_swap_b32 %0, %1" : "+v"(F1), "+v"(H1));
                uint4 fw = make_uint4(F0, F1, H0, H1);
                bf16x8 pf = *(bf16x8*)&fw;
                int g = kt * 4 + hh * 2 + hi;
                bf16x8 vf = *(const bf16x8*)&smem[vbase + ((g ^ vswz) << 3)];
                if (hh) ob = __builtin_amdgcn_mfma_f32_32x32x16_bf16(vf, pf, ob, 0, 0, 0);
                else    oa = __builtin_amdgcn_mfma_f32_32x32x16_bf16(vf, pf, oa, 0, 0, 0);
            }
        }

        l_run += __shfl_xor(l_run, 32, 64);
        float rinv = 1.0f / l_run;

        // epilogue: G2/GO2 [h][s][q][32]; o[r] -> c = 4*hi + (r&3) + 8*(r>>2)
        const size_t grow = ((size_t)h << 21) + ((size_t)s << 13) + ((q0 + l31) << 5) + hi * 4;
#pragma unroll
        for (int g = 0; g < 4; ++g) {
            ushort4 gv = *(const ushort4*)&G[grow + g * 8];
            float o0 = (oa[4 * g + 0] + ob[4 * g + 0]) * rinv * bf2f(gv.x);
            float o1 = (oa[4 * g + 1] + ob[4 * g + 1]) * rinv * bf2f(gv.y);
            float o2 = (oa[4 * g + 2] + ob[4 * g + 2]) * rinv * bf2f(gv.z);
            float o3 = (oa[4 * g + 3] + ob[4 * g + 3]) * rinv * bf2f(gv.w);
            ushort4 ov;
            ov.x = f2bf(o0); ov.y = f2bf(o1); ov.z = f2bf(o2); ov.w = f2bf(o3);
            *(ushort4*)&GO[grow + g * 8] = ov;
        }
    }
}

// -------------------------------------------------------------- output GEMM
// GO2 [h][m][32] (m = s*256+q) @ WoT^T + bo -> out fp32; 128x128 tile,
// double-buffered LDS staging (BK=64).
__global__ __launch_bounds__(256) void out_gemm_kernel(const ushort* __restrict__ GO,
                                                       const ushort* __restrict__ WoT,
                                                       const float* __restrict__ bo,
                                                       float* __restrict__ out) {
    __shared__ ushort SH[32768];
    int bid = blockIdx.x;
    int wid = ((bid & 7) << 7) | (bid >> 3);
    int by = wid >> 1, bx = wid & 1;
    int m0 = by << 7, n0 = bx << 7;
    int t = threadIdx.x, lane = t & 63, w = t >> 6;
    int l15 = lane & 15, l4 = lane >> 4;
    int wr = w >> 1, wc = w & 1;

    int srow  = t >> 3;
    int scolh = (((lane & 7) ^ ((lane >> 3) & 7)) << 3);
    // A element (m, k): addr = (k>>5)<<21 | m<<5 | (k&31); k = kt*64 + scolh
    const ushort* Ag = GO + ((size_t)(scolh >> 5) << 21) + ((size_t)(m0 + srow) << 5) + (scolh & 31);
    const ushort* Bg = WoT + (size_t)(n0 + srow) * 256 + scolh;

    auto stage = [&](int kt) {
        int k0 = kt << 6;
        int bufo = (kt & 1) << 14;
#pragma unroll
        for (int i = 0; i < 4; ++i) {
            gload16(Ag + ((size_t)kt << 22) + (i << 10), &SH[bufo + t * 8 + i * 2048]);
            gload16(Bg + (size_t)(i * 32) * 256 + k0, &SH[bufo + 8192 + t * 8 + i * 2048]);
        }
    };

    f32x4 acc[4][4] = {};
    stage(0);

    for (int kt = 0; kt < 4; ++kt) {
        __syncthreads();
        if (kt < 3) stage(kt + 1);
        int bufo = (kt & 1) << 14;
#pragma unroll
        for (int ks = 0; ks < 2; ++ks) {
            int xr = ks * 4 + l4;
            bf16x8 af[4], bfr[4];
#pragma unroll
            for (int mi = 0; mi < 4; ++mi) {
                int row = wr * 64 + mi * 16 + l15;
                af[mi] = *(const bf16x8*)&SH[bufo + row * 64 + ((xr ^ (l15 & 7)) << 3)];
            }
#pragma unroll
            for (int ni = 0; ni < 4; ++ni) {
                int row = wc * 64 + ni * 16 + l15;
                bfr[ni] = *(const bf16x8*)&SH[bufo + 8192 + row * 64 + ((xr ^ (l15 & 7)) << 3)];
            }
#pragma unroll
            for (int mi = 0; mi < 4; ++mi)
#pragma unroll
                for (int ni = 0; ni < 4; ++ni)
                    acc[mi][ni] = __builtin_amdgcn_mfma_f32_16x16x32_bf16(af[mi], bfr[ni], acc[mi][ni], 0, 0, 0);
        }
    }

    int crow0 = m0 + wr * 64 + l4 * 4;
#pragma unroll
    for (int ni = 0; ni < 4; ++ni) {
        int col = n0 + wc * 64 + ni * 16 + l15;
        float bov = bo[col];
#pragma unroll
        for (int mi = 0; mi < 4; ++mi)
#pragma unroll
            for (int r = 0; r < 4; ++r)
                out[(size_t)(crow0 + mi * 16 + r) * 256 + col] = acc[mi][ni][r] + bov;
    }
}

// ------------------------------------------------------------------- launch
extern "C" void kernel_launch(void* const* d_in, const int* in_sizes, int n_in,
                              void* d_out, int out_size, void* d_ws, size_t ws_size,
                              hipStream_t stream) {
    const float* m      = (const float*)d_in[0];
    const float* z      = (const float*)d_in[1];
    const float* ln_m_w = (const float*)d_in[2];
    const float* ln_m_b = (const float*)d_in[3];
    const float* ln_z_w = (const float*)d_in[4];
    const float* ln_z_b = (const float*)d_in[5];
    const float* Wz     = (const float*)d_in[6];
    const float* Wq     = (const float*)d_in[7];
    const float* Wk     = (const float*)d_in[8];
    const float* Wv     = (const float*)d_in[9];
    const float* Wg     = (const float*)d_in[10];
    const float* bg     = (const float*)d_in[11];
    const float* Wo     = (const float*)d_in[12];
    const float* bo     = (const float*)d_in[13];
    float* out = (float*)d_out;

    char* ws = (char*)d_ws;
    ushort* Wt    = (ushort*)(ws + 0);            //  524288 B
    ushort* WoT   = (ushort*)(ws + 524288);       //  131072 B
    ushort* biasb = (ushort*)(ws + 655360);       // 1048576 B (bf16, region reserves 2MB)
    ushort* mn    = (ushort*)(ws + 2752512);      // 33554432 B (aliased with GO)
    ushort* GO    = mn;
    ushort* Q     = (ushort*)(ws + 36306944);     // 33554432 B
    ushort* K     = (ushort*)(ws + 69861376);     // 33554432 B
    ushort* Vt    = (ushort*)(ws + 103415808);    // 33554432 B
    ushort* G     = (ushort*)(ws + 136970240);    // 33554432 B

    pre_kernel<<<19712, 256, 0, stream>>>(m, ln_m_w, ln_m_b, z, ln_z_w, ln_z_b,
                                          Wz, Wq, Wk, Wv, Wg, Wo,
                                          mn, biasb, Wt, WoT);
    proj_gemm_kernel<<<4096, 256, 0, stream>>>(mn, Wt, bg, Q, K, Vt, G);
    attn_kernel<<<512, 512, 0, stream>>>(Q, K, Vt, G, biasb, GO);
    out_gemm_kernel<<<1024, 256, 0, stream>>>(GO, WoT, bo, out);
}